// Round 2
// baseline (37.119 us; speedup 1.0000x reference)
//
#include <hip/hip_runtime.h>

// B=4, N=4096, D=64, depth=2 (fp32).
// out = MLP_dec( Y (Y^T Y) ), Y = rownorm(MLP_enc(x))   [associativity rewrite]
//
// R2 change: eliminate LDS-broadcast reads (the R1 bottleneck).
//  - W_enc/W_dec/G read via wave-uniform indices -> compiler emits s_load (SMEM),
//    freeing the per-CU LDS pipe. v_fma takes the SGPR operand directly.
//  - Gram's broadcast operand fetched with v_readlane from registers (VALU)
//    instead of ds_read_b128 broadcast.
//  - LDS keeps only the inter-layer row transposes (conflict-free patterns).

constexpr int THREADS = 512;   // 8 waves; lane r = t&63 (row), q = t>>6 (col-eighth)

#define RFL(v) __builtin_amdgcn_readfirstlane(v)

__device__ __forceinline__ float readlane_f(float v, int lane) {
    return __int_as_float(__builtin_amdgcn_readlane(__float_as_int(v), lane));
}

// ---------------- K1: enc MLP + row-normalize + Gram partials ----------------
__global__ __launch_bounds__(512) void k_enc(const float* __restrict__ x,
                                             const float* __restrict__ W,
                                             float* __restrict__ y,
                                             float* __restrict__ partG) {
    __shared__ float sT[64][68];   // 17-granule row stride: even b128 bank spread
    __shared__ float sSq[64][8];

    const int t = threadIdx.x, r = t & 63;
    const int q = RFL(t >> 6);                 // wave-uniform -> SGPR
    const int blk = blockIdx.x;                // 64-row tile; batch = blk>>6
    const long base = (long)blk * 4096;

    // stage x tile (coalesced float4)
    const float4* xv = (const float4*)(x + base);
#pragma unroll
    for (int i = 0; i < 2; ++i) {
        const int e = t + i * 512;             // 0..1023 float4s
        const float4 v = xv[e];
        *(float4*)&sT[e >> 4][(e & 15) * 4] = v;
    }
    __syncthreads();

    float xr[64];
#pragma unroll
    for (int i = 0; i < 16; ++i) {
        const float4 v = *(const float4*)&sT[r][4 * i];
        xr[4*i] = v.x; xr[4*i+1] = v.y; xr[4*i+2] = v.z; xr[4*i+3] = v.w;
    }

    // ---- enc layer 1 (weights via s_load: uniform index)
    float h[8];
#pragma unroll
    for (int oo = 0; oo < 8; ++oo) {
        const float* wr = W + (q * 8 + oo) * 64;
        float acc = 0.f;
#pragma unroll
        for (int i = 0; i < 64; ++i) acc = fmaf(xr[i], wr[i], acc);
        h[oo] = fmaxf(acc, 0.f);
    }
    __syncthreads();                           // all xr reads done before overwrite
#pragma unroll
    for (int oo = 0; oo < 8; ++oo) sT[r][q * 8 + oo] = h[oo];
    __syncthreads();

    // ---- enc layer 2
#pragma unroll
    for (int i = 0; i < 16; ++i) {
        const float4 v = *(const float4*)&sT[r][4 * i];
        xr[4*i] = v.x; xr[4*i+1] = v.y; xr[4*i+2] = v.z; xr[4*i+3] = v.w;
    }
#pragma unroll
    for (int oo = 0; oo < 8; ++oo) {
        const float* wr = W + 4096 + (q * 8 + oo) * 64;
        float acc = 0.f;
#pragma unroll
        for (int i = 0; i < 64; ++i) acc = fmaf(xr[i], wr[i], acc);
        h[oo] = fmaxf(acc, 0.f);
    }

    // ---- row norm
    float ss = 0.f;
#pragma unroll
    for (int j = 0; j < 8; ++j) ss += h[j] * h[j];
    sSq[r][q] = ss;
    __syncthreads();                           // also: all h1 reads finished
    float tot = 0.f;
#pragma unroll
    for (int j = 0; j < 8; ++j) tot += sSq[r][j];
    const float scale = 1.f / (sqrtf(tot) + 1e-6f);
    float ys[8];
#pragma unroll
    for (int j = 0; j < 8; ++j) { ys[j] = h[j] * scale; sT[r][q * 8 + j] = ys[j]; }
    __syncthreads();

    // ---- write y (coalesced via sT)
    float4* yv = (float4*)(y + base);
#pragma unroll
    for (int i = 0; i < 2; ++i) {
        const int e = t + i * 512;
        yv[e] = *(const float4*)&sT[e >> 4][(e & 15) * 4];
    }

    // ---- Gram partial G[r][8q..]: a from LDS (conflict-free b32),
    //      b from registers via readlane (VALU, keeps LDS pipe free)
    float g[8] = {0.f, 0.f, 0.f, 0.f, 0.f, 0.f, 0.f, 0.f};
#pragma unroll
    for (int row = 0; row < 64; ++row) {
        const float a = sT[row][r];
#pragma unroll
        for (int j = 0; j < 8; ++j)
            g[j] = fmaf(a, readlane_f(ys[j], row), g[j]);
    }
    float* pg = partG + (long)blk * 4096 + r * 64 + q * 8;
    *(float4*)pg       = make_float4(g[0], g[1], g[2], g[3]);
    *(float4*)(pg + 4) = make_float4(g[4], g[5], g[6], g[7]);
}

// ---------------- K_red: sum 64 tile-partials per batch -> G[4][64][64] -----
__global__ __launch_bounds__(256) void k_redG(const float* __restrict__ partG,
                                              float* __restrict__ G) {
    const int e = blockIdx.x * 256 + threadIdx.x;   // 0..4095 float4 outputs
    const int b = e >> 10, idx = e & 1023;
    const float4* src = (const float4*)partG;
    float4 s = make_float4(0.f, 0.f, 0.f, 0.f);
#pragma unroll 8
    for (int j = 0; j < 64; ++j) {
        const float4 v = src[(long)(b * 64 + j) * 1024 + idx];
        s.x += v.x; s.y += v.y; s.z += v.z; s.w += v.w;
    }
    ((float4*)G)[e] = s;
}

// ---------------- K2: z = y*G (G via s_load), then dec MLP -------------------
__global__ __launch_bounds__(512) void k_dec(const float* __restrict__ y,
                                             const float* __restrict__ G,
                                             const float* __restrict__ W,
                                             float* __restrict__ out) {
    __shared__ float sT[64][68];

    const int t = threadIdx.x, r = t & 63;
    const int q = RFL(t >> 6);
    const int blk = blockIdx.x, bb = blk >> 6;
    const long base = (long)blk * 4096;
    const float* Gb = G + bb * 4096;

    // stage y tile
    const float4* yv = (const float4*)(y + base);
#pragma unroll
    for (int i = 0; i < 2; ++i) {
        const int e = t + i * 512;
        *(float4*)&sT[e >> 4][(e & 15) * 4] = yv[e];
    }
    __syncthreads();

    float yr[64];
#pragma unroll
    for (int i = 0; i < 16; ++i) {
        const float4 v = *(const float4*)&sT[r][4 * i];
        yr[4*i] = v.x; yr[4*i+1] = v.y; yr[4*i+2] = v.z; yr[4*i+3] = v.w;
    }

    // ---- z[d] = sum_k y[k] * G[k][d]  (G via s_load)
    float z[8] = {0.f, 0.f, 0.f, 0.f, 0.f, 0.f, 0.f, 0.f};
#pragma unroll
    for (int k = 0; k < 64; ++k) {
        const float* gk = Gb + k * 64 + q * 8;      // uniform -> s_load dwordx8
        const float a = yr[k];
#pragma unroll
        for (int j = 0; j < 8; ++j) z[j] = fmaf(a, gk[j], z[j]);
    }
    __syncthreads();                                // yr reads done
#pragma unroll
    for (int j = 0; j < 8; ++j) sT[r][q * 8 + j] = z[j];
    __syncthreads();

    // ---- dec layer 1
#pragma unroll
    for (int i = 0; i < 16; ++i) {
        const float4 v = *(const float4*)&sT[r][4 * i];
        yr[4*i] = v.x; yr[4*i+1] = v.y; yr[4*i+2] = v.z; yr[4*i+3] = v.w;
    }
    float h[8];
#pragma unroll
    for (int oo = 0; oo < 8; ++oo) {
        const float* wr = W + (q * 8 + oo) * 64;
        float acc = 0.f;
#pragma unroll
        for (int i = 0; i < 64; ++i) acc = fmaf(yr[i], wr[i], acc);
        h[oo] = fmaxf(acc, 0.f);
    }
    __syncthreads();                                // z reads done
#pragma unroll
    for (int oo = 0; oo < 8; ++oo) sT[r][q * 8 + oo] = h[oo];
    __syncthreads();

    // ---- dec layer 2 -> out (direct register store)
#pragma unroll
    for (int i = 0; i < 16; ++i) {
        const float4 v = *(const float4*)&sT[r][4 * i];
        yr[4*i] = v.x; yr[4*i+1] = v.y; yr[4*i+2] = v.z; yr[4*i+3] = v.w;
    }
    float o8[8];
#pragma unroll
    for (int oo = 0; oo < 8; ++oo) {
        const float* wr = W + 4096 + (q * 8 + oo) * 64;
        float acc = 0.f;
#pragma unroll
        for (int i = 0; i < 64; ++i) acc = fmaf(yr[i], wr[i], acc);
        o8[oo] = fmaxf(acc, 0.f);
    }
    float* po = out + base + r * 64 + q * 8;
    *(float4*)po       = make_float4(o8[0], o8[1], o8[2], o8[3]);
    *(float4*)(po + 4) = make_float4(o8[4], o8[5], o8[6], o8[7]);
}

extern "C" void kernel_launch(void* const* d_in, const int* in_sizes, int n_in,
                              void* d_out, int out_size, void* d_ws, size_t ws_size,
                              hipStream_t stream) {
    const float* x     = (const float*)d_in[0];   // [4,4096,64]
    const float* W_enc = (const float*)d_in[1];   // [2,64,64]
    const float* W_dec = (const float*)d_in[2];   // [2,64,64]
    float* out = (float*)d_out;                   // [4,4096,64] fp32
    float* ws  = (float*)d_ws;                    // >= 8.5 MB (observed ~268 MB)

    const size_t Y_ELEMS = 4ull * 4096 * 64;      // 1,048,576
    float* y     = ws;
    float* partG = ws + Y_ELEMS;                  // [256][4096]
    float* G     = partG + Y_ELEMS;               // [4][4096]

    k_enc <<<256, THREADS, 0, stream>>>(x, W_enc, y, partG);
    k_redG<<<16, 256, 0, stream>>>(partG, G);
    k_dec <<<256, THREADS, 0, stream>>>(y, G, W_dec, out);
}